// Round 14
// baseline (357.682 us; speedup 1.0000x reference)
//
#include <hip/hip_runtime.h>

typedef __attribute__((ext_vector_type(8))) short s16x8;
typedef __attribute__((ext_vector_type(4))) float f32x4;

#define MFMA16 __builtin_amdgcn_mfma_f32_16x16x32_bf16
#define WAITVM(N) asm volatile("s_waitcnt vmcnt(" #N ")" ::: "memory")
#define SBAR() asm volatile("s_barrier" ::: "memory")
#define WAITLGKM0() asm volatile("s_waitcnt lgkmcnt(0)" ::: "memory")
#define SCHEDB() __builtin_amdgcn_sched_barrier(0)

__device__ __forceinline__ short f2bf(float x) {
  union { float f; unsigned u; } c; c.f = x;
  unsigned r = (c.u + 0x7fffu + ((c.u >> 16) & 1u)) >> 16;
  return (short)r;
}

__device__ __forceinline__ void gld16(const void* g, void* l) {
  __builtin_amdgcn_global_load_lds(
      (const __attribute__((address_space(1))) unsigned*)g,
      (__attribute__((address_space(3))) unsigned*)l, 16, 0, 0);
}

// BK=32 LDS tiles: involution slot ^= (row>>1)&3 on BOTH gld_lds source and
// ds_read (R3-verified, 0 bank conflicts):
//   stage: srow = lane>>2, selem = ((lane&3)^((lane>>3)&3))*8
//   read : koff = ((lane>>4)^((lane>>1)&3))*8
// Race discipline (R8-proven): wave-private strips restage the just-consumed
// buffer only AFTER the MFMAs, pinned by sched_barrier(0). Cross-wave LDS
// region reuse: lgkmcnt(0)+s_barrier on both sides.
// k_s1 C-epilogue (R14): C-tile staged in the freed 32KB K-loop LDS with
// chunk involution q' = q ^ (u&7); read side is bank-quad = q8^(u&7) ->
// 8 lanes/quad = b128 minimum (conflict-free); each thread then stores one
// (u,w) A2 row as 8 contiguous b128 globals.

// ---------------------------------------------------------------------------
// Prep
// ---------------------------------------------------------------------------
__global__ __launch_bounds__(256) void k_cvt_l1(const float* __restrict__ L1,
                                                short* __restrict__ L1b) {
  int i = blockIdx.x * 256 + threadIdx.x;
  L1b[i] = f2bf(L1[i]);
}

__global__ __launch_bounds__(256) void k_build_l2cat(const float* __restrict__ L2,
                                                     short* __restrict__ L2cat) {
  __shared__ float t[32][33];
  const int l = blockIdx.z, w0 = blockIdx.x * 32, z0 = blockIdx.y * 32;
  const int tx = threadIdx.x, ty = threadIdx.y;
  const float* src = L2 + (size_t)l * 65536;
  for (int i = ty; i < 32; i += 8) t[i][tx] = src[(size_t)(w0 + i) * 256 + z0 + tx];
  __syncthreads();
  for (int i = ty; i < 32; i += 8)
    L2cat[(size_t)(z0 + i) * 768 + l * 256 + w0 + tx] = f2bf(t[tx][i]);
}

__global__ __launch_bounds__(256) void k_build_wt(const float* __restrict__ W,
                                                  short* __restrict__ WT) {
  for (int idx = threadIdx.x + blockIdx.x * 256; idx < 192 * 192; idx += 256 * gridDim.x) {
    int lo = idx / 192, kf = idx % 192;
    int l = lo / 64, o = lo & 63, k = kf / 64, f = kf & 63;
    WT[idx] = f2bf(W[(((size_t)(k * 3 + l) * 64 + f) << 6) + o]);
  }
}

__global__ __launch_bounds__(256) void k_cvt_ht(const float* __restrict__ H,
                                                short* __restrict__ HbT, int b0) {
  __shared__ float t[32][33];
  const int bc = blockIdx.z;
  const int wf0 = blockIdx.x * 32, v0 = blockIdx.y * 32;
  const int tx = threadIdx.x, ty = threadIdx.y;
  const float* src = H + ((size_t)(b0 + bc) * 256 + v0) * 16384;
  for (int i = ty; i < 32; i += 8) t[i][tx] = src[(size_t)i * 16384 + wf0 + tx];
  __syncthreads();
  short* dst = HbT + ((size_t)bc * 16384 + wf0) * 256;
  for (int i = ty; i < 32; i += 8) dst[(size_t)i * 256 + v0 + tx] = f2bf(t[tx][i]);
}

// ---------------------------------------------------------------------------
// S1: A2[((bc*256+u)*256+w)*192 + kk*64+f] = sum_v L1b[kk][u][v]*HbT[bc][w*64+f][v]
// 128x128 tile, BK=32, double-buffered (R5-proven K-loop) + LDS-staged
// coalesced epilogue (R14).
// ---------------------------------------------------------------------------
__global__ __launch_bounds__(256, 4) void k_s1(const short* __restrict__ L1b,
                                               const short* __restrict__ HbT,
                                               short* __restrict__ A2) {
  __shared__ __align__(16) short SB[16384];  // 32 KB: K-loop tiles, then C-tile
  short* At = SB;          // [2][128*32]
  short* Bt = SB + 8192;   // [2][128*32]
  const int t = threadIdx.x, lane = t & 63, wid = t >> 6;
  const int n0 = blockIdx.x * 128;
  const int kk = blockIdx.y >> 1;
  const int u0 = (blockIdx.y & 1) * 128;
  const int bc = blockIdx.z;
  const short* Ag = L1b + (size_t)kk * 65536;
  const short* Bg = HbT + (size_t)bc * 16384 * 256;
  const int wm = wid >> 1, wn = wid & 1;
  const int srow = lane >> 2;
  const int selem = ((lane & 3) ^ ((lane >> 3) & 3)) * 8;
  const int koff = ((lane >> 4) ^ ((lane >> 1) & 3)) * 8;
  const int ar = lane & 15;
#pragma unroll
  for (int j = 0; j < 2; ++j) {
    const int rb = wid * 32 + j * 16;
    gld16(Ag + (size_t)(u0 + rb + srow) * 256 + selem, At + rb * 32);
    gld16(Bg + (size_t)(n0 + rb + srow) * 256 + selem, Bt + rb * 32);
  }
  __syncthreads();
  f32x4 acc[4][4] = {};
#pragma unroll
  for (int kt8 = 0; kt8 < 8; ++kt8) {
    const int cur = (kt8 & 1) * 4096;
    s16x8 a[4], b[4];
#pragma unroll
    for (int i = 0; i < 4; ++i)
      a[i] = *(const s16x8*)&At[cur + (wm * 64 + i * 16 + ar) * 32 + koff];
#pragma unroll
    for (int j = 0; j < 4; ++j)
      b[j] = *(const s16x8*)&Bt[cur + (wn * 64 + j * 16 + ar) * 32 + koff];
    if (kt8 < 7) {
      const int nxt = ((kt8 + 1) & 1) * 4096;
#pragma unroll
      for (int j = 0; j < 2; ++j) {
        const int rb = wid * 32 + j * 16;
        gld16(Ag + (size_t)(u0 + rb + srow) * 256 + (kt8 + 1) * 32 + selem, At + nxt + rb * 32);
        gld16(Bg + (size_t)(n0 + rb + srow) * 256 + (kt8 + 1) * 32 + selem, Bt + nxt + rb * 32);
      }
    }
#pragma unroll
    for (int i = 0; i < 4; ++i)
#pragma unroll
      for (int j = 0; j < 4; ++j) acc[i][j] = MFMA16(a[i], b[j], acc[i][j], 0, 0, 0);
    __syncthreads();
  }
  // ---- epilogue: C-tile -> LDS (chunk involution), then coalesced stores ----
  // Ct[u][128 f']: addr = u*128 + ((f>>3)^(u&7))*8 + (f&7); f = wn*64+j*16+cc
  const int cr = lane >> 4, cc = lane & 15;
#pragma unroll
  for (int i = 0; i < 4; ++i) {
    const int ubase = wm * 64 + i * 16 + cr * 4;
#pragma unroll
    for (int j = 0; j < 4; ++j) {
      const int f = wn * 64 + j * 16 + cc;
#pragma unroll
      for (int r = 0; r < 4; ++r) {
        const int u = ubase + r;
        SB[u * 128 + (((f >> 3) ^ (u & 7)) << 3) + (f & 7)] = f2bf(acc[i][j][r]);
      }
    }
  }
  __syncthreads();
  // thread t: u = t>>1, h = t&1 -> A2 row (u0+u, w = blockIdx.x*2+h), 64 f.
  const int u_l = t >> 1, h = t & 1;
  short* dst = A2 + (((size_t)bc * 256 + u0 + u_l) * 256 + blockIdx.x * 2 + h) * 192 + kk * 64;
#pragma unroll
  for (int q8 = 0; q8 < 8; ++q8) {
    const int chunk = (h * 8 + q8) ^ (u_l & 7);
    *(float4*)(dst + q8 * 8) = *(const float4*)&SB[u_l * 128 + chunk * 8];
  }
}

// ---------------------------------------------------------------------------
// S2+S3 fused (R12-exact), one block per bu, L-SPLIT into 3 passes, LDS 80 KB,
// 2 blocks/CU. vmcnt ladders: phase1 VM(4),4,4,4,2,0; phase2 VM(4)x6,2,0.
// ---------------------------------------------------------------------------
__global__ __launch_bounds__(512, 4) void k_s23(const short* __restrict__ A2,
                                                const short* __restrict__ WTg,
                                                const short* __restrict__ L2cat,
                                                const float* __restrict__ bias,
                                                float* __restrict__ out, int b0) {
  __shared__ __align__(16) short P[64 * 256];        // 32 KB; Ws_l overlays [0,24K)
  __shared__ __align__(16) short AtS[8][3][32 * 32]; // 48 KB strips
  short* Ws = P;
  const int t = threadIdx.x, lane = t & 63, wid = t >> 6;
  const int bul = blockIdx.x;
  const int ar = lane & 15, cc = ar, cr = lane >> 4, sl = lane & 7, ks = lane >> 4;
  const int srow = lane >> 2;
  const int selem = ((lane & 3) ^ ((lane >> 3) & 3)) * 8;
  const int koff = ((lane >> 4) ^ ((lane >> 1) & 3)) * 8;
  const short* A2g = A2 + (size_t)bul * 49152;

#define P1S(tt, bi)                                                                        \
  do {                                                                                     \
    gld16(A2g + (size_t)(wid * 32 + srow) * 192 + (tt) * 32 + selem, &AtS[wid][bi][0]);    \
    gld16(A2g + (size_t)(wid * 32 + 16 + srow) * 192 + (tt) * 32 + selem,                  \
          &AtS[wid][bi][512]);                                                             \
  } while (0)
#define P2S(tt, bi)                                                                        \
  do {                                                                                     \
    gld16(L2cat + (size_t)(wid * 32 + srow) * 768 + (tt) * 32 + selem, &AtS[wid][bi][0]);  \
    gld16(L2cat + (size_t)(wid * 32 + 16 + srow) * 768 + (tt) * 32 + selem,                \
          &AtS[wid][bi][512]);                                                             \
  } while (0)

  f32x4 acc2[2][4] = {};
#pragma unroll
  for (int l = 0; l < 3; ++l) {
    const short* WTl = WTg + (size_t)l * 64 * 192;
    for (int s = wid; s < 24; s += 8) {
      const int t6 = s / 4, g = (s & 3) * 16;
      gld16(WTl + (size_t)(g + srow) * 192 + t6 * 32 + selem, Ws + ((size_t)t6 * 64 + g) * 32);
    }
    P1S(0, 0);
    P1S(1, 1);
    P1S(2, 2);
    WAITVM(6);  // Ws_l landed (strips may be in flight)
    SBAR();     // Ws_l resident block-wide

    // ---- Phase 1_l: (64 o) x (own 32 w), K=192, 6 iters ----
    f32x4 acc[4][2] = {};
#pragma unroll
    for (int kt6 = 0; kt6 < 6; ++kt6) {
      if (kt6 < 4) { WAITVM(4); } else if (kt6 == 4) { WAITVM(2); } else { WAITVM(0); }
      const short* stc = &AtS[wid][kt6 % 3][0];
      s16x8 a0 = *(const s16x8*)&stc[(0 + ar) * 32 + koff];
      s16x8 a1 = *(const s16x8*)&stc[(16 + ar) * 32 + koff];
#pragma unroll
      for (int j2 = 0; j2 < 4; ++j2) {
        s16x8 b = *(const s16x8*)&Ws[((size_t)kt6 * 64 + j2 * 16 + ar) * 32 + koff];
        acc[j2][0] = MFMA16(a0, b, acc[j2][0], 0, 0, 0);
        acc[j2][1] = MFMA16(a1, b, acc[j2][1], 0, 0, 0);
      }
      SCHEDB();  // pin restage after MFMAs (this iter's strip consumed)
      if (kt6 == 0) { P1S(3, 0); } else if (kt6 == 1) { P1S(4, 1); } else if (kt6 == 2) { P1S(5, 2); }
    }
    WAITLGKM0();  // this wave's Ws_l/strip ds_reads complete
    SBAR();       // all waves done reading Ws_l; region becomes P_l

    // phase-2 strip prefetch (strips fully consumed; overlaps P writes)
    P2S(l * 8 + 0, 0);
    P2S(l * 8 + 1, 1);
    P2S(l * 8 + 2, 2);

    // acc -> P_l (packed b32, swizzled slots: slot = (w>>3) ^ (o&7))
#pragma unroll
    for (int j2 = 0; j2 < 4; ++j2)
#pragma unroll
      for (int i = 0; i < 2; ++i)
#pragma unroll
        for (int rp = 0; rp < 2; ++rp) {
          const int r = rp * 2;
          const int w = wid * 32 + i * 16 + cr * 4 + r;
          const int o = j2 * 16 + cc;
          const int addr = o * 256 + (((w >> 3) ^ (o & 7)) << 3) + (w & 7);
          unsigned lo16 = (unsigned short)f2bf(acc[j2][i][r]);
          unsigned hi16 = (unsigned short)f2bf(acc[j2][i][r + 1]);
          *(unsigned*)&P[addr] = lo16 | (hi16 << 16);
        }
    WAITLGKM0();  // P_l ds_writes drained (gld_lds is vmcnt, unaffected)
    SBAR();       // P_l visible block-wide

    // ---- Phase 2_l: (own 32 z) x (64 o), K=256, 8 iters, acc2 += ----
#pragma unroll
    for (int t2 = 0; t2 < 8; ++t2) {
      if (t2 < 6) { WAITVM(4); } else if (t2 == 6) { WAITVM(2); } else { WAITVM(0); }
      const short* stc = &AtS[wid][t2 % 3][0];
      s16x8 a0 = *(const s16x8*)&stc[(0 + ar) * 32 + koff];
      s16x8 a1 = *(const s16x8*)&stc[(16 + ar) * 32 + koff];
      const int S = t2 * 4 + ks;
#pragma unroll
      for (int j = 0; j < 4; ++j) {
        s16x8 b = *(const s16x8*)&P[(j * 16 + ar) * 256 + ((S ^ sl) << 3)];
        acc2[0][j] = MFMA16(a0, b, acc2[0][j], 0, 0, 0);
        acc2[1][j] = MFMA16(a1, b, acc2[1][j], 0, 0, 0);
      }
      SCHEDB();  // pin restage after MFMAs
      if (t2 < 5) {
        if (t2 % 3 == 0) { P2S(l * 8 + t2 + 3, 0); }
        else if (t2 % 3 == 1) { P2S(l * 8 + t2 + 3, 1); }
        else { P2S(l * 8 + t2 + 3, 2); }
      }
    }
    if (l < 2) {
      WAITLGKM0();  // this wave's P_l reads complete
      SBAR();       // all waves done with P_l; region can become Ws_{l+1}
    }
  }
#undef P1S
#undef P2S

  // epilogue
  float* og = out + ((size_t)b0 * 256 + bul) * 16384;
#pragma unroll
  for (int i = 0; i < 2; ++i)
#pragma unroll
    for (int j = 0; j < 4; ++j) {
      const float bv = bias[j * 16 + cc];
#pragma unroll
      for (int r = 0; r < 4; ++r) {
        const int z = wid * 32 + i * 16 + cr * 4 + r;
        og[(size_t)z * 64 + j * 16 + cc] = fmaxf(acc2[i][j][r] + bv, 0.f);
      }
    }
}

// ---------------------------------------------------------------------------
extern "C" void kernel_launch(void* const* d_in, const int* in_sizes, int n_in,
                              void* d_out, int out_size, void* d_ws, size_t ws_size,
                              hipStream_t stream) {
  const float* H    = (const float*)d_in[0];
  const float* L1   = (const float*)d_in[1];
  const float* L2   = (const float*)d_in[2];
  const float* W    = (const float*)d_in[3];
  const float* bias = (const float*)d_in[4];
  float* out = (float*)d_out;

  char* ws = (char*)d_ws;
  short* L1b   = (short*)ws;                  // 384 KB
  short* L2cat = (short*)(ws + (384 << 10));  // 384 KB
  short* WT    = (short*)(ws + (768 << 10));  // 72 KB
  char* data = ws + (4ull << 20);

  // per-batch: HbT 8 MiB + A2 24 MiB = 32 MiB
  const size_t perb = 32ull << 20;
  size_t avail = (ws_size > (4ull << 20)) ? ws_size - (4ull << 20) : 0;
  int nb = 1;
  if (avail >= 8 * perb) nb = 8;
  else if (avail >= 4 * perb) nb = 4;
  else if (avail >= 2 * perb) nb = 2;

  short* HbT = (short*)data;
  short* A2  = (short*)(data + (size_t)nb * (8ull << 20));

  k_cvt_l1<<<768, 256, 0, stream>>>(L1, L1b);
  k_build_l2cat<<<dim3(8, 8, 3), dim3(32, 8), 0, stream>>>(L2, L2cat);
  k_build_wt<<<36, 256, 0, stream>>>(W, WT);

  for (int b0 = 0; b0 < 8; b0 += nb) {
    k_cvt_ht<<<dim3(512, 8, nb), dim3(32, 8), 0, stream>>>(H, HbT, b0);
    k_s1<<<dim3(128, 6, nb), 256, 0, stream>>>(L1b, HbT, A2);
    k_s23<<<nb * 256, 512, 0, stream>>>(A2, WT, L2cat, bias, out, b0);
  }
}

// Round 15
// 288.516 us; speedup vs baseline: 1.2397x; 1.2397x over previous
//
#include <hip/hip_runtime.h>

typedef __attribute__((ext_vector_type(8))) short s16x8;
typedef __attribute__((ext_vector_type(4))) float f32x4;

#define MFMA16 __builtin_amdgcn_mfma_f32_16x16x32_bf16
#define WAITVM(N) asm volatile("s_waitcnt vmcnt(" #N ")" ::: "memory")
#define SBAR() asm volatile("s_barrier" ::: "memory")
#define WAITLGKM0() asm volatile("s_waitcnt lgkmcnt(0)" ::: "memory")
#define SCHEDB() __builtin_amdgcn_sched_barrier(0)

__device__ __forceinline__ short f2bf(float x) {
  union { float f; unsigned u; } c; c.f = x;
  unsigned r = (c.u + 0x7fffu + ((c.u >> 16) & 1u)) >> 16;
  return (short)r;
}

__device__ __forceinline__ void gld16(const void* g, void* l) {
  __builtin_amdgcn_global_load_lds(
      (const __attribute__((address_space(1))) unsigned*)g,
      (__attribute__((address_space(3))) unsigned*)l, 16, 0, 0);
}

// BK=32 LDS tiles: involution slot ^= (row>>1)&3 on BOTH gld_lds source and
// ds_read (R3-verified, 0 bank conflicts):
//   stage: srow = lane>>2, selem = ((lane&3)^((lane>>3)&3))*8
//   read : koff = ((lane>>4)^((lane>>1)&3))*8
// Race discipline (R8-proven): wave-private strips restage the just-consumed
// buffer only AFTER the MFMAs, pinned by sched_barrier(0). Cross-wave LDS
// region reuse: lgkmcnt(0)+s_barrier on both sides.

// ---------------------------------------------------------------------------
// Prep
// ---------------------------------------------------------------------------
__global__ __launch_bounds__(256) void k_cvt_l1(const float* __restrict__ L1,
                                                short* __restrict__ L1b) {
  int i = blockIdx.x * 256 + threadIdx.x;
  L1b[i] = f2bf(L1[i]);
}

__global__ __launch_bounds__(256) void k_build_l2cat(const float* __restrict__ L2,
                                                     short* __restrict__ L2cat) {
  __shared__ float t[32][33];
  const int l = blockIdx.z, w0 = blockIdx.x * 32, z0 = blockIdx.y * 32;
  const int tx = threadIdx.x, ty = threadIdx.y;
  const float* src = L2 + (size_t)l * 65536;
  for (int i = ty; i < 32; i += 8) t[i][tx] = src[(size_t)(w0 + i) * 256 + z0 + tx];
  __syncthreads();
  for (int i = ty; i < 32; i += 8)
    L2cat[(size_t)(z0 + i) * 768 + l * 256 + w0 + tx] = f2bf(t[tx][i]);
}

__global__ __launch_bounds__(256) void k_build_wt(const float* __restrict__ W,
                                                  short* __restrict__ WT) {
  for (int idx = threadIdx.x + blockIdx.x * 256; idx < 192 * 192; idx += 256 * gridDim.x) {
    int lo = idx / 192, kf = idx % 192;
    int l = lo / 64, o = lo & 63, k = kf / 64, f = kf & 63;
    WT[idx] = f2bf(W[(((size_t)(k * 3 + l) * 64 + f) << 6) + o]);
  }
}

// HbT[bc][wf][v] = bf16(H[b0+bc][v][wf]); 64-v x 32-wf tiles, short2 writes.
__global__ __launch_bounds__(256) void k_cvt_ht(const float* __restrict__ H,
                                                short* __restrict__ HbT, int b0) {
  __shared__ float t[64][33];
  const int bc = blockIdx.z;
  const int wf0 = blockIdx.x * 32, v0 = blockIdx.y * 64;
  const int tx = threadIdx.x, ty = threadIdx.y;
  const float* src = H + ((size_t)(b0 + bc) * 256 + v0) * 16384;
  for (int i = ty; i < 64; i += 8) t[i][tx] = src[(size_t)i * 16384 + wf0 + tx];
  __syncthreads();
  short* dst = HbT + ((size_t)bc * 16384 + wf0) * 256 + v0;
  for (int i = ty; i < 32; i += 8) {
    unsigned lo16 = (unsigned short)f2bf(t[tx * 2][i]);
    unsigned hi16 = (unsigned short)f2bf(t[tx * 2 + 1][i]);
    *(unsigned*)&dst[(size_t)i * 256 + tx * 2] = lo16 | (hi16 << 16);
  }
}

// ---------------------------------------------------------------------------
// S1: A2[((bc*256+u)*256+w)*192 + kk*64+f] = sum_v L1b[kk][u][v]*HbT[bc][w*64+f][v]
// 256x128 tile (R15: block covers all 256 u for one kk -> B-tile staged once,
// half the B fetch), BK=32, 8 waves (4x2), double-buffered, stage-before-MFMA,
// syncthreads. Per-wave 64x64 tile/epilogue identical to the R12-proven form.
// ---------------------------------------------------------------------------
__global__ __launch_bounds__(512, 3) void k_s1(const short* __restrict__ L1b,
                                               const short* __restrict__ HbT,
                                               short* __restrict__ A2) {
  __shared__ __align__(16) short At[2][256 * 32];  // 32 KB
  __shared__ __align__(16) short Bt[2][128 * 32];  // 16 KB
  const int t = threadIdx.x, lane = t & 63, wid = t >> 6;
  const int n0 = blockIdx.x * 128;
  const int kk = blockIdx.y;
  const int bc = blockIdx.z;
  const short* Ag = L1b + (size_t)kk * 65536;
  const short* Bg = HbT + (size_t)bc * 16384 * 256;
  const int wm = wid >> 1, wn = wid & 1;
  const int srow = lane >> 2;
  const int selem = ((lane & 3) ^ ((lane >> 3) & 3)) * 8;
  const int koff = ((lane >> 4) ^ ((lane >> 1) & 3)) * 8;
  const int ar = lane & 15;
#define S1STAGE(kt, bi)                                                                   \
  do {                                                                                    \
    const int ra0 = wid * 32, ra1 = wid * 32 + 16, rb = wid * 16;                         \
    gld16(Ag + (size_t)(ra0 + srow) * 256 + (kt) * 32 + selem, At[bi] + ra0 * 32);        \
    gld16(Ag + (size_t)(ra1 + srow) * 256 + (kt) * 32 + selem, At[bi] + ra1 * 32);        \
    gld16(Bg + (size_t)(n0 + rb + srow) * 256 + (kt) * 32 + selem, Bt[bi] + rb * 32);     \
  } while (0)
  S1STAGE(0, 0);
  __syncthreads();
  f32x4 acc[4][4] = {};
#pragma unroll
  for (int kt8 = 0; kt8 < 8; ++kt8) {
    const int cur = kt8 & 1;
    s16x8 a[4], b[4];
#pragma unroll
    for (int i = 0; i < 4; ++i)
      a[i] = *(const s16x8*)&At[cur][(wm * 64 + i * 16 + ar) * 32 + koff];
#pragma unroll
    for (int j = 0; j < 4; ++j)
      b[j] = *(const s16x8*)&Bt[cur][(wn * 64 + j * 16 + ar) * 32 + koff];
    if (kt8 < 7) { S1STAGE(kt8 + 1, cur ^ 1); }
#pragma unroll
    for (int i = 0; i < 4; ++i)
#pragma unroll
      for (int j = 0; j < 4; ++j) acc[i][j] = MFMA16(a[i], b[j], acc[i][j], 0, 0, 0);
    __syncthreads();
  }
#undef S1STAGE
  const int cr = lane >> 4, cc = lane & 15;
#pragma unroll
  for (int i = 0; i < 4; ++i)
#pragma unroll
    for (int j = 0; j < 4; ++j) {
      const int ncol = n0 + wn * 64 + j * 16 + cc;
      const int w = ncol >> 6, f = ncol & 63;
#pragma unroll
      for (int r = 0; r < 4; ++r) {
        const int u = wm * 64 + i * 16 + cr * 4 + r;
        A2[(((size_t)bc * 256 + u) * 256 + w) * 192 + kk * 64 + f] = f2bf(acc[i][j][r]);
      }
    }
}

// ---------------------------------------------------------------------------
// S2+S3 fused (R12-exact), one block per bu, L-SPLIT into 3 passes, LDS 80 KB,
// 2 blocks/CU. vmcnt ladders: phase1 VM(4),4,4,4,2,0; phase2 VM(4)x6,2,0.
// ---------------------------------------------------------------------------
__global__ __launch_bounds__(512, 4) void k_s23(const short* __restrict__ A2,
                                                const short* __restrict__ WTg,
                                                const short* __restrict__ L2cat,
                                                const float* __restrict__ bias,
                                                float* __restrict__ out, int b0) {
  __shared__ __align__(16) short P[64 * 256];        // 32 KB; Ws_l overlays [0,24K)
  __shared__ __align__(16) short AtS[8][3][32 * 32]; // 48 KB strips
  short* Ws = P;
  const int t = threadIdx.x, lane = t & 63, wid = t >> 6;
  const int bul = blockIdx.x;
  const int ar = lane & 15, cc = ar, cr = lane >> 4, sl = lane & 7, ks = lane >> 4;
  const int srow = lane >> 2;
  const int selem = ((lane & 3) ^ ((lane >> 3) & 3)) * 8;
  const int koff = ((lane >> 4) ^ ((lane >> 1) & 3)) * 8;
  const short* A2g = A2 + (size_t)bul * 49152;

#define P1S(tt, bi)                                                                        \
  do {                                                                                     \
    gld16(A2g + (size_t)(wid * 32 + srow) * 192 + (tt) * 32 + selem, &AtS[wid][bi][0]);    \
    gld16(A2g + (size_t)(wid * 32 + 16 + srow) * 192 + (tt) * 32 + selem,                  \
          &AtS[wid][bi][512]);                                                             \
  } while (0)
#define P2S(tt, bi)                                                                        \
  do {                                                                                     \
    gld16(L2cat + (size_t)(wid * 32 + srow) * 768 + (tt) * 32 + selem, &AtS[wid][bi][0]);  \
    gld16(L2cat + (size_t)(wid * 32 + 16 + srow) * 768 + (tt) * 32 + selem,                \
          &AtS[wid][bi][512]);                                                             \
  } while (0)

  f32x4 acc2[2][4] = {};
#pragma unroll
  for (int l = 0; l < 3; ++l) {
    const short* WTl = WTg + (size_t)l * 64 * 192;
    for (int s = wid; s < 24; s += 8) {
      const int t6 = s / 4, g = (s & 3) * 16;
      gld16(WTl + (size_t)(g + srow) * 192 + t6 * 32 + selem, Ws + ((size_t)t6 * 64 + g) * 32);
    }
    P1S(0, 0);
    P1S(1, 1);
    P1S(2, 2);
    WAITVM(6);  // Ws_l landed (strips may be in flight)
    SBAR();     // Ws_l resident block-wide

    // ---- Phase 1_l: (64 o) x (own 32 w), K=192, 6 iters ----
    f32x4 acc[4][2] = {};
#pragma unroll
    for (int kt6 = 0; kt6 < 6; ++kt6) {
      if (kt6 < 4) { WAITVM(4); } else if (kt6 == 4) { WAITVM(2); } else { WAITVM(0); }
      const short* stc = &AtS[wid][kt6 % 3][0];
      s16x8 a0 = *(const s16x8*)&stc[(0 + ar) * 32 + koff];
      s16x8 a1 = *(const s16x8*)&stc[(16 + ar) * 32 + koff];
#pragma unroll
      for (int j2 = 0; j2 < 4; ++j2) {
        s16x8 b = *(const s16x8*)&Ws[((size_t)kt6 * 64 + j2 * 16 + ar) * 32 + koff];
        acc[j2][0] = MFMA16(a0, b, acc[j2][0], 0, 0, 0);
        acc[j2][1] = MFMA16(a1, b, acc[j2][1], 0, 0, 0);
      }
      SCHEDB();  // pin restage after MFMAs (this iter's strip consumed)
      if (kt6 == 0) { P1S(3, 0); } else if (kt6 == 1) { P1S(4, 1); } else if (kt6 == 2) { P1S(5, 2); }
    }
    WAITLGKM0();  // this wave's Ws_l/strip ds_reads complete
    SBAR();       // all waves done reading Ws_l; region becomes P_l

    // phase-2 strip prefetch (strips fully consumed; overlaps P writes)
    P2S(l * 8 + 0, 0);
    P2S(l * 8 + 1, 1);
    P2S(l * 8 + 2, 2);

    // acc -> P_l (packed b32, swizzled slots: slot = (w>>3) ^ (o&7))
#pragma unroll
    for (int j2 = 0; j2 < 4; ++j2)
#pragma unroll
      for (int i = 0; i < 2; ++i)
#pragma unroll
        for (int rp = 0; rp < 2; ++rp) {
          const int r = rp * 2;
          const int w = wid * 32 + i * 16 + cr * 4 + r;
          const int o = j2 * 16 + cc;
          const int addr = o * 256 + (((w >> 3) ^ (o & 7)) << 3) + (w & 7);
          unsigned lo16 = (unsigned short)f2bf(acc[j2][i][r]);
          unsigned hi16 = (unsigned short)f2bf(acc[j2][i][r + 1]);
          *(unsigned*)&P[addr] = lo16 | (hi16 << 16);
        }
    WAITLGKM0();  // P_l ds_writes drained (gld_lds is vmcnt, unaffected)
    SBAR();       // P_l visible block-wide

    // ---- Phase 2_l: (own 32 z) x (64 o), K=256, 8 iters, acc2 += ----
#pragma unroll
    for (int t2 = 0; t2 < 8; ++t2) {
      if (t2 < 6) { WAITVM(4); } else if (t2 == 6) { WAITVM(2); } else { WAITVM(0); }
      const short* stc = &AtS[wid][t2 % 3][0];
      s16x8 a0 = *(const s16x8*)&stc[(0 + ar) * 32 + koff];
      s16x8 a1 = *(const s16x8*)&stc[(16 + ar) * 32 + koff];
      const int S = t2 * 4 + ks;
#pragma unroll
      for (int j = 0; j < 4; ++j) {
        s16x8 b = *(const s16x8*)&P[(j * 16 + ar) * 256 + ((S ^ sl) << 3)];
        acc2[0][j] = MFMA16(a0, b, acc2[0][j], 0, 0, 0);
        acc2[1][j] = MFMA16(a1, b, acc2[1][j], 0, 0, 0);
      }
      SCHEDB();  // pin restage after MFMAs
      if (t2 < 5) {
        if (t2 % 3 == 0) { P2S(l * 8 + t2 + 3, 0); }
        else if (t2 % 3 == 1) { P2S(l * 8 + t2 + 3, 1); }
        else { P2S(l * 8 + t2 + 3, 2); }
      }
    }
    if (l < 2) {
      WAITLGKM0();  // this wave's P_l reads complete
      SBAR();       // all waves done with P_l; region can become Ws_{l+1}
    }
  }
#undef P1S
#undef P2S

  // epilogue
  float* og = out + ((size_t)b0 * 256 + bul) * 16384;
#pragma unroll
  for (int i = 0; i < 2; ++i)
#pragma unroll
    for (int j = 0; j < 4; ++j) {
      const float bv = bias[j * 16 + cc];
#pragma unroll
      for (int r = 0; r < 4; ++r) {
        const int z = wid * 32 + i * 16 + cr * 4 + r;
        og[(size_t)z * 64 + j * 16 + cc] = fmaxf(acc2[i][j][r] + bv, 0.f);
      }
    }
}

// ---------------------------------------------------------------------------
extern "C" void kernel_launch(void* const* d_in, const int* in_sizes, int n_in,
                              void* d_out, int out_size, void* d_ws, size_t ws_size,
                              hipStream_t stream) {
  const float* H    = (const float*)d_in[0];
  const float* L1   = (const float*)d_in[1];
  const float* L2   = (const float*)d_in[2];
  const float* W    = (const float*)d_in[3];
  const float* bias = (const float*)d_in[4];
  float* out = (float*)d_out;

  char* ws = (char*)d_ws;
  short* L1b   = (short*)ws;                  // 384 KB
  short* L2cat = (short*)(ws + (384 << 10));  // 384 KB
  short* WT    = (short*)(ws + (768 << 10));  // 72 KB
  char* data = ws + (4ull << 20);

  // per-batch: HbT 8 MiB + A2 24 MiB = 32 MiB
  const size_t perb = 32ull << 20;
  size_t avail = (ws_size > (4ull << 20)) ? ws_size - (4ull << 20) : 0;
  int nb = 1;
  if (avail >= 8 * perb) nb = 8;
  else if (avail >= 4 * perb) nb = 4;
  else if (avail >= 2 * perb) nb = 2;

  short* HbT = (short*)data;
  short* A2  = (short*)(data + (size_t)nb * (8ull << 20));

  k_cvt_l1<<<768, 256, 0, stream>>>(L1, L1b);
  k_build_l2cat<<<dim3(8, 8, 3), dim3(32, 8), 0, stream>>>(L2, L2cat);
  k_build_wt<<<36, 256, 0, stream>>>(W, WT);

  for (int b0 = 0; b0 < 8; b0 += nb) {
    k_cvt_ht<<<dim3(512, 4, nb), dim3(32, 8), 0, stream>>>(H, HbT, b0);
    k_s1<<<dim3(128, 3, nb), 512, 0, stream>>>(L1b, HbT, A2);
    k_s23<<<nb * 256, 512, 0, stream>>>(A2, WT, L2cat, bias, out, b0);
  }
}